// Round 1
// baseline (4371.309 us; speedup 1.0000x reference)
//
#include <hip/hip_runtime.h>
#include <math.h>

// Problem constants (reference: B=8, N=40962, D=40, H=512, D_DYN=32, 4 steps, dt=0.1)
constexpr int BB   = 8;
constexpr int NN   = 40962;
constexpr int DDIM = 40;     // feature dim
constexpr int HH   = 512;    // hidden
constexpr int DDYN = 32;     // dynamic (updated) dims
constexpr int KDIM = 4 * DDIM;  // 160 contraction length
constexpr int TM   = 16;     // nodes per block
constexpr float STEPSZ = 0.1f;

__device__ __forceinline__ float gelu_tanh(float v) {
    // JAX default: approximate=True (tanh form)
    const float c = 0.7978845608028654f;  // sqrt(2/pi)
    float t = tanhf(c * (v + 0.044715f * v * v * v));
    return 0.5f * v * (1.0f + t);
}

__global__ __launch_bounds__(256) void step_kernel(
    const float* __restrict__ xsrc, float* __restrict__ xdst,
    const int*  __restrict__ index,
    const float* __restrict__ W1, const float* __restrict__ b1,
    const float* __restrict__ W2, const float* __restrict__ b2)
{
    __shared__ float z_lds[TM][KDIM];   // 16*160*4 = 10 KiB
    __shared__ float h_lds[TM][HH];     // 16*512*4 = 32 KiB
    __shared__ float fz_lds[TM][DDYN];  // 2 KiB

    const int tid  = threadIdx.x;
    const int tile = blockIdx.x;
    const int b    = blockIdx.y;
    const int n0   = tile * TM;
    const int nvalid = min(TM, NN - n0);

    // ---- Phase 1: gather z[m][k*D+d] = xsrc[b, index[n0+m, k], d] ----
    // TM nodes * 4 neighbors * 10 float4s = 640 float4 loads
    for (int e = tid; e < TM * 4 * 10; e += 256) {
        int m = e / 40;        // node within tile
        int r = e % 40;
        int k = r / 10;        // neighbor slot
        int q = r % 10;        // float4 within the 40-float row
        float4 v = make_float4(0.f, 0.f, 0.f, 0.f);
        int n = n0 + m;
        if (n < NN) {
            int nb = index[n * 4 + k];
            const float4* src = (const float4*)(xsrc + ((size_t)b * NN + nb) * DDIM);
            v = src[q];
        }
        ((float4*)&z_lds[m][k * DDIM])[q] = v;
    }
    __syncthreads();

    // ---- Phase 2: GEMM1  h[m][c] = gelu(z[m,:] . W1[:,c] + b1[c]) ----
    // thread owns columns c0, c0+1 for all TM nodes
    const int c0 = 2 * tid;
    float2 acc[TM];
    {
        float bx = b1[c0];
        float by = b1[c0 + 1];
        #pragma unroll
        for (int m = 0; m < TM; ++m) { acc[m].x = bx; acc[m].y = by; }
    }
    for (int kd = 0; kd < KDIM; kd += 4) {
        float2 w0 = *(const float2*)(W1 + (size_t)(kd + 0) * HH + c0);
        float2 w1 = *(const float2*)(W1 + (size_t)(kd + 1) * HH + c0);
        float2 w2 = *(const float2*)(W1 + (size_t)(kd + 2) * HH + c0);
        float2 w3 = *(const float2*)(W1 + (size_t)(kd + 3) * HH + c0);
        #pragma unroll
        for (int m = 0; m < TM; ++m) {
            float4 zv = *(const float4*)&z_lds[m][kd];   // broadcast read
            acc[m].x = fmaf(zv.x, w0.x, acc[m].x);
            acc[m].y = fmaf(zv.x, w0.y, acc[m].y);
            acc[m].x = fmaf(zv.y, w1.x, acc[m].x);
            acc[m].y = fmaf(zv.y, w1.y, acc[m].y);
            acc[m].x = fmaf(zv.z, w2.x, acc[m].x);
            acc[m].y = fmaf(zv.z, w2.y, acc[m].y);
            acc[m].x = fmaf(zv.w, w3.x, acc[m].x);
            acc[m].y = fmaf(zv.w, w3.y, acc[m].y);
        }
    }
    #pragma unroll
    for (int m = 0; m < TM; ++m) {
        h_lds[m][c0]     = gelu_tanh(acc[m].x);
        h_lds[m][c0 + 1] = gelu_tanh(acc[m].y);
    }
    __syncthreads();

    // ---- Phase 3: GEMM2  fz[m][j] = h[m,:] . W2[:,j] + b2[j] ----
    // 256 threads -> (m, j) and (m+8, j), j = tid&31, m = tid>>5
    {
        const int j  = tid & 31;
        const int mg = tid >> 5;   // 0..7
        float a0 = b2[j];
        float a1 = a0;
        for (int c = 0; c < HH; c += 4) {
            float wa = W2[(size_t)(c + 0) * DDYN + j];
            float wb = W2[(size_t)(c + 1) * DDYN + j];
            float wc = W2[(size_t)(c + 2) * DDYN + j];
            float wd = W2[(size_t)(c + 3) * DDYN + j];
            float4 h0 = *(const float4*)&h_lds[mg][c];
            float4 h1 = *(const float4*)&h_lds[mg + 8][c];
            a0 = fmaf(h0.x, wa, a0); a0 = fmaf(h0.y, wb, a0);
            a0 = fmaf(h0.z, wc, a0); a0 = fmaf(h0.w, wd, a0);
            a1 = fmaf(h1.x, wa, a1); a1 = fmaf(h1.y, wb, a1);
            a1 = fmaf(h1.z, wc, a1); a1 = fmaf(h1.w, wd, a1);
        }
        fz_lds[mg][j]     = a0;
        fz_lds[mg + 8][j] = a1;
    }
    __syncthreads();

    // ---- Phase 4: x update (contiguous rows for this tile) ----
    const size_t base = ((size_t)b * NN + n0) * (size_t)DDIM;
    const int total = nvalid * DDIM;
    for (int e = tid; e < total; e += 256) {
        int m = e / DDIM;
        int d = e % DDIM;
        float v = xsrc[base + e];
        if (d < DDYN) v = fmaf(STEPSZ, fz_lds[m][d], v);
        xdst[base + e] = v;
    }
}

extern "C" void kernel_launch(void* const* d_in, const int* in_sizes, int n_in,
                              void* d_out, int out_size, void* d_ws, size_t ws_size,
                              hipStream_t stream) {
    const float* x   = (const float*)d_in[0];
    const int*   idx = (const int*)  d_in[1];
    const float* W1  = (const float*)d_in[2];
    const float* b1  = (const float*)d_in[3];
    const float* W2  = (const float*)d_in[4];
    const float* b2  = (const float*)d_in[5];
    float* out = (float*)d_out;
    float* ws  = (float*)d_ws;   // one x-sized ping-pong buffer (52.4 MB)

    dim3 grid((NN + TM - 1) / TM, BB);
    dim3 block(256);

    // 4 sequential steps, ping-pong so the final result lands in d_out
    step_kernel<<<grid, block, 0, stream>>>(x,   ws,  idx, W1, b1, W2, b2);
    step_kernel<<<grid, block, 0, stream>>>(ws,  out, idx, W1, b1, W2, b2);
    step_kernel<<<grid, block, 0, stream>>>(out, ws,  idx, W1, b1, W2, b2);
    step_kernel<<<grid, block, 0, stream>>>(ws,  out, idx, W1, b1, W2, b2);
}

// Round 2
// 736.548 us; speedup vs baseline: 5.9349x; 5.9349x over previous
//
#include <hip/hip_runtime.h>
#include <math.h>

// B=8, N=40962, D=40, H=512, D_DYN=32, 4 steps, dt=0.1
constexpr int BB   = 8;
constexpr int NN   = 40962;
constexpr int DDIM = 40;
constexpr int HH   = 512;
constexpr int DDYN = 32;
constexpr float STEPSZ = 0.1f;

constexpr int TM   = 64;      // nodes per block (MFMA path)
constexpr int NTHR = 512;     // 8 waves
constexpr int ZS   = 168;     // z LDS row stride in bf16 elems (pad 160->168: 2-way banks, 16B aligned)

constexpr size_t X_ELEMS = (size_t)BB * NN * DDIM;       // 13,107,840
constexpr size_t X_BYTES = X_ELEMS * 4;                  // 52,431,360
constexpr int W1P_ELEMS = 5 * 32 * 4 * 16 * 8;           // 81920
constexpr int W2P_ELEMS = 16 * 2 * 4 * 16 * 8;           // 16384

typedef __attribute__((ext_vector_type(8))) short short8;
typedef __attribute__((ext_vector_type(4))) float f32x4;
typedef __attribute__((ext_vector_type(4))) unsigned short u16x4;

__device__ __forceinline__ unsigned short bf16_rne(float f) {
    unsigned int u = __float_as_uint(f);
    unsigned int r = (u + 0x7FFFu + ((u >> 16) & 1u)) >> 16;
    return (unsigned short)r;
}

__device__ __forceinline__ float gelu_fast(float x) {
    // 0.5x(1+tanh(0.79788456(x+0.044715x^3))) == x / (1 + e^{-1.59576912(x+0.044715x^3)})
    float u = x * fmaf(0.044715f, x * x, 1.0f);
    float e = __expf(-1.5957691216057308f * u);
    return x * __builtin_amdgcn_rcpf(1.0f + e);
}

// ---- weight packing: fragment-order bf16 ----
// W1p[kk(5)][ct(32)][q(4)][nl(16)][j(8)] = bf16(W1[kk*32+q*8+j][ct*16+nl])
__global__ __launch_bounds__(256) void pack_w1(const float* __restrict__ W1,
                                               unsigned short* __restrict__ W1p) {
    int t = blockIdx.x * 256 + threadIdx.x;
    if (t >= W1P_ELEMS) return;
    int j = t & 7, nl = (t >> 3) & 15, q = (t >> 7) & 3, ct = (t >> 9) & 31, kk = t >> 14;
    int k = kk * 32 + q * 8 + j, col = ct * 16 + nl;
    W1p[t] = bf16_rne(W1[(size_t)k * HH + col]);
}
// W2p[kk(16)][jt(2)][q(4)][nl(16)][j(8)] = bf16(W2[kk*32+q*8+j][jt*16+nl])
__global__ __launch_bounds__(256) void pack_w2(const float* __restrict__ W2,
                                               unsigned short* __restrict__ W2p) {
    int t = blockIdx.x * 256 + threadIdx.x;
    if (t >= W2P_ELEMS) return;
    int j = t & 7, nl = (t >> 3) & 15, q = (t >> 7) & 3, jt = (t >> 9) & 1, kk = t >> 10;
    int k = kk * 32 + q * 8 + j, col = jt * 16 + nl;
    W2p[t] = bf16_rne(W2[(size_t)k * DDYN + col]);
}

// h LDS: 64 rows x 512 bf16 = 64KB exactly, XOR-swizzled 16B chunks:
// addr_bytes(row, col) = row*1024 + (((col>>3) ^ (row & 7)) << 4) + (col & 7)*2
__device__ __forceinline__ int h_addr_elem(int row, int col) {
    return row * 512 + ((((col >> 3) ^ (row & 7)) << 3) | (col & 7));
}

__global__ __launch_bounds__(NTHR, 4) void step_mfma(
    const float* __restrict__ xsrc, float* __restrict__ xdst,
    const int* __restrict__ index,
    const unsigned short* __restrict__ W1p, const float* __restrict__ b1,
    const unsigned short* __restrict__ W2p, const float* __restrict__ b2)
{
    __shared__ alignas(16) unsigned short smem[TM * HH];  // 65536 B; z overlays the front
    unsigned short* z = smem;   // TM x ZS bf16 (21504 B), dead after GEMM1
    unsigned short* h = smem;   // TM x 512 bf16 swizzled

    const int tid = threadIdx.x;
    const int w   = tid >> 6;     // wave 0..7
    const int ln  = tid & 63;
    const int nl  = ln & 15;      // lane&15
    const int q   = ln >> 4;      // quad 0..3
    const int n0  = blockIdx.x * TM;
    const int b   = blockIdx.y;
    const size_t xbase = (size_t)b * NN * DDIM;

    // ---- Phase 1: gather -> z (bf16) ----
    for (int e = tid; e < TM * 4 * 10; e += NTHR) {
        int m = e / 40, r = e - m * 40;
        int k = r / 10, qq = r - k * 10;
        u16x4 out = (u16x4)0;
        int n = n0 + m;
        if (n < NN) {
            int nb = index[n * 4 + k];
            const float4* src = (const float4*)(xsrc + xbase + (size_t)nb * DDIM);
            float4 v = src[qq];
            out.x = bf16_rne(v.x); out.y = bf16_rne(v.y);
            out.z = bf16_rne(v.z); out.w = bf16_rne(v.w);
        }
        *(u16x4*)(z + m * ZS + k * 40 + qq * 4) = out;
    }
    __syncthreads();

    // ---- Phase 2: GEMM1  acc[rt][ct] (rows=nodes, cols=w*64+ct*16+nl) ----
    f32x4 acc[4][4];
    #pragma unroll
    for (int ct = 0; ct < 4; ++ct) {
        float bv = b1[w * 64 + ct * 16 + nl];
        f32x4 a; a[0] = bv; a[1] = bv; a[2] = bv; a[3] = bv;
        #pragma unroll
        for (int rt = 0; rt < 4; ++rt) acc[rt][ct] = a;
    }
    for (int kk = 0; kk < 5; ++kk) {
        short8 afr[4];
        #pragma unroll
        for (int rt = 0; rt < 4; ++rt)
            afr[rt] = *(const short8*)(z + (rt * 16 + nl) * ZS + kk * 32 + q * 8);
        #pragma unroll
        for (int ct = 0; ct < 4; ++ct) {
            short8 bfr = *(const short8*)(W1p + (size_t)((((kk * 32 + (w * 4 + ct)) * 4 + q) * 16 + nl) * 8));
            #pragma unroll
            for (int rt = 0; rt < 4; ++rt)
                acc[rt][ct] = __builtin_amdgcn_mfma_f32_16x16x32_bf16(afr[rt], bfr, acc[rt][ct], 0, 0, 0);
        }
    }
    __syncthreads();   // everyone done reading z before h overwrites it

    // ---- Phase 3: h = gelu(acc) -> LDS (swizzled) ----
    #pragma unroll
    for (int rt = 0; rt < 4; ++rt)
        #pragma unroll
        for (int ct = 0; ct < 4; ++ct) {
            int col = w * 64 + ct * 16 + nl;
            #pragma unroll
            for (int i = 0; i < 4; ++i) {
                int row = rt * 16 + q * 4 + i;
                h[h_addr_elem(row, col)] = bf16_rne(gelu_fast(acc[rt][ct][i]));
            }
        }
    __syncthreads();

    // ---- Phase 4: GEMM2 as fz^T = W2^T . h^T  (m=j, n=node) ----
    const int jt = w >> 2, nt = w & 3;
    f32x4 acc2;
    {
        const float4 bv = *(const float4*)(b2 + jt * 16 + q * 4);
        acc2[0] = bv.x; acc2[1] = bv.y; acc2[2] = bv.z; acc2[3] = bv.w;
    }
    const int hrow = nt * 16 + nl;       // node row in h
    #pragma unroll
    for (int kk = 0; kk < 16; ++kk) {
        short8 afr = *(const short8*)(W2p + (size_t)((((kk * 2 + jt) * 4 + q) * 16 + nl) * 8));
        // 8 contiguous cols within one 16B swizzled chunk: chunk = kk*4+q
        int chunk = ((kk * 4 + q) ^ (hrow & 7));
        short8 bfr = *(const short8*)(h + hrow * 512 + chunk * 8);
        acc2 = __builtin_amdgcn_mfma_f32_16x16x32_bf16(afr, bfr, acc2, 0, 0, 0);
    }

    // ---- Phase 5: epilogue. lane holds fz[node=nt*16+nl][j=jt*16+q*4+i] ----
    {
        int n = n0 + nt * 16 + nl;
        if (n < NN) {
            size_t off = xbase + (size_t)n * DDIM + jt * 16 + q * 4;
            float4 v = *(const float4*)(xsrc + off);
            v.x = fmaf(STEPSZ, acc2[0], v.x);
            v.y = fmaf(STEPSZ, acc2[1], v.y);
            v.z = fmaf(STEPSZ, acc2[2], v.z);
            v.w = fmaf(STEPSZ, acc2[3], v.w);
            *(float4*)(xdst + off) = v;
        }
    }
    // static cols 32..39 passthrough
    for (int t = tid; t < TM * 2; t += NTHR) {
        int m = t >> 1;
        int n = n0 + m;
        if (n < NN) {
            size_t off = xbase + (size_t)n * DDIM + 32 + (t & 1) * 4;
            *(float4*)(xdst + off) = *(const float4*)(xsrc + off);
        }
    }
}

// ================= fallback f32 path (used only if ws too small) =================
constexpr int FTM = 16;
__global__ __launch_bounds__(256) void step_f32(
    const float* __restrict__ xsrc, float* __restrict__ xdst,
    const int* __restrict__ index,
    const float* __restrict__ W1, const float* __restrict__ b1,
    const float* __restrict__ W2, const float* __restrict__ b2)
{
    __shared__ float z_lds[FTM][160];
    __shared__ float h_lds[FTM][HH];
    __shared__ float fz_lds[FTM][DDYN];
    const int tid = threadIdx.x, tile = blockIdx.x, b = blockIdx.y;
    const int n0 = tile * FTM;
    const int nvalid = min(FTM, NN - n0);
    for (int e = tid; e < FTM * 4 * 10; e += 256) {
        int m = e / 40, r = e % 40, k = r / 10, qq = r % 10;
        float4 v = make_float4(0.f, 0.f, 0.f, 0.f);
        int n = n0 + m;
        if (n < NN) {
            int nb = index[n * 4 + k];
            v = ((const float4*)(xsrc + ((size_t)b * NN + nb) * DDIM))[qq];
        }
        ((float4*)&z_lds[m][k * DDIM])[qq] = v;
    }
    __syncthreads();
    const int c0 = 2 * tid;
    float2 acc[FTM];
    {
        float bx = b1[c0], by = b1[c0 + 1];
        #pragma unroll
        for (int m = 0; m < FTM; ++m) { acc[m].x = bx; acc[m].y = by; }
    }
    for (int kd = 0; kd < 160; kd += 4) {
        float2 w0 = *(const float2*)(W1 + (size_t)(kd + 0) * HH + c0);
        float2 w1 = *(const float2*)(W1 + (size_t)(kd + 1) * HH + c0);
        float2 w2 = *(const float2*)(W1 + (size_t)(kd + 2) * HH + c0);
        float2 w3 = *(const float2*)(W1 + (size_t)(kd + 3) * HH + c0);
        #pragma unroll
        for (int m = 0; m < FTM; ++m) {
            float4 zv = *(const float4*)&z_lds[m][kd];
            acc[m].x = fmaf(zv.x, w0.x, acc[m].x); acc[m].y = fmaf(zv.x, w0.y, acc[m].y);
            acc[m].x = fmaf(zv.y, w1.x, acc[m].x); acc[m].y = fmaf(zv.y, w1.y, acc[m].y);
            acc[m].x = fmaf(zv.z, w2.x, acc[m].x); acc[m].y = fmaf(zv.z, w2.y, acc[m].y);
            acc[m].x = fmaf(zv.w, w3.x, acc[m].x); acc[m].y = fmaf(zv.w, w3.y, acc[m].y);
        }
    }
    #pragma unroll
    for (int m = 0; m < FTM; ++m) {
        h_lds[m][c0]     = gelu_fast(acc[m].x);
        h_lds[m][c0 + 1] = gelu_fast(acc[m].y);
    }
    __syncthreads();
    {
        const int j = tid & 31, mg = tid >> 5;
        float a0 = b2[j], a1 = a0;
        for (int c = 0; c < HH; c += 4) {
            float wa = W2[(size_t)(c + 0) * DDYN + j];
            float wb = W2[(size_t)(c + 1) * DDYN + j];
            float wc = W2[(size_t)(c + 2) * DDYN + j];
            float wd = W2[(size_t)(c + 3) * DDYN + j];
            float4 h0 = *(const float4*)&h_lds[mg][c];
            float4 h1 = *(const float4*)&h_lds[mg + 8][c];
            a0 = fmaf(h0.x, wa, a0); a0 = fmaf(h0.y, wb, a0);
            a0 = fmaf(h0.z, wc, a0); a0 = fmaf(h0.w, wd, a0);
            a1 = fmaf(h1.x, wa, a1); a1 = fmaf(h1.y, wb, a1);
            a1 = fmaf(h1.z, wc, a1); a1 = fmaf(h1.w, wd, a1);
        }
        fz_lds[mg][j] = a0; fz_lds[mg + 8][j] = a1;
    }
    __syncthreads();
    const size_t base = ((size_t)b * NN + n0) * (size_t)DDIM;
    for (int e = tid; e < nvalid * DDIM; e += 256) {
        int m = e / DDIM, d = e % DDIM;
        float v = xsrc[base + e];
        if (d < DDYN) v = fmaf(STEPSZ, fz_lds[m][d], v);
        xdst[base + e] = v;
    }
}

extern "C" void kernel_launch(void* const* d_in, const int* in_sizes, int n_in,
                              void* d_out, int out_size, void* d_ws, size_t ws_size,
                              hipStream_t stream) {
    const float* x   = (const float*)d_in[0];
    const int*   idx = (const int*)  d_in[1];
    const float* W1  = (const float*)d_in[2];
    const float* b1  = (const float*)d_in[3];
    const float* W2  = (const float*)d_in[4];
    const float* b2  = (const float*)d_in[5];
    float* out  = (float*)d_out;
    float* xbuf = (float*)d_ws;

    const size_t need = X_BYTES + (size_t)(W1P_ELEMS + W2P_ELEMS) * 2;
    if (ws_size >= need) {
        unsigned short* W1p = (unsigned short*)((char*)d_ws + X_BYTES);
        unsigned short* W2p = W1p + W1P_ELEMS;
        pack_w1<<<(W1P_ELEMS + 255) / 256, 256, 0, stream>>>(W1, W1p);
        pack_w2<<<(W2P_ELEMS + 255) / 256, 256, 0, stream>>>(W2, W2p);
        dim3 grid((NN + TM - 1) / TM, BB), block(NTHR);
        step_mfma<<<grid, block, 0, stream>>>(x,    xbuf, idx, W1p, b1, W2p, b2);
        step_mfma<<<grid, block, 0, stream>>>(xbuf, out,  idx, W1p, b1, W2p, b2);
        step_mfma<<<grid, block, 0, stream>>>(out,  xbuf, idx, W1p, b1, W2p, b2);
        step_mfma<<<grid, block, 0, stream>>>(xbuf, out,  idx, W1p, b1, W2p, b2);
    } else {
        dim3 grid((NN + FTM - 1) / FTM, BB), block(256);
        step_f32<<<grid, block, 0, stream>>>(x,    xbuf, idx, W1, b1, W2, b2);
        step_f32<<<grid, block, 0, stream>>>(xbuf, out,  idx, W1, b1, W2, b2);
        step_f32<<<grid, block, 0, stream>>>(out,  xbuf, idx, W1, b1, W2, b2);
        step_f32<<<grid, block, 0, stream>>>(xbuf, out,  idx, W1, b1, W2, b2);
    }
}